// Round 11
// baseline (200.402 us; speedup 1.0000x reference)
//
#include <hip/hip_runtime.h>

// R15 = R14 wave-level code in 512-thread / 8-sample / 64KB blocks -> 2
// independent barrier domains per CU. One block's barrier-heavy dense phase
// overlaps the other block's gauss chains; DS bursts de-lockstep; generation
// boundaries stagger instead of draining the whole CU.
// Kept from R14: bias in MFMA C-operand, cvt_pkrtz epilogues, K=16 S2/S4
// stages (no zero-init needed), depth-1 weight prefetch, DS-only sched fences.

typedef _Float16 f16x8 __attribute__((ext_vector_type(8)));
typedef _Float16 f16x4 __attribute__((ext_vector_type(4)));
typedef __fp16   hf2   __attribute__((ext_vector_type(2)));   // cvt_pkrtz result type
typedef float    f32x4 __attribute__((ext_vector_type(4)));

// ws layout (halves): wm0 tiled [128][80][32]; K~ [4][64][64]; padded weights
#define KT_OFF    327680
#define W0P_OFF   344064               // [16][64], rows>=8 zero
#define W1P_OFF   345088               // [16][16], cols>=8 zero
#define W2P_OFF   345344               // [32][16], all valid
#define W3P_OFF   345856               // [64][32]

__global__ void prep_all(const float* __restrict__ s0, const float* __restrict__ s1,
                         const float* __restrict__ s2, const float* __restrict__ s3,
                         const float* __restrict__ w0, const float* __restrict__ w1,
                         const float* __restrict__ w2, const float* __restrict__ w3,
                         const float* __restrict__ wm0, _Float16* __restrict__ base) {
  int bid = blockIdx.x, tid = threadIdx.x;
  if (bid < 1280) {
    // wm0 fp32 [80][4096] -> fp16 tiled [kc][n][32]
    int idx = bid * 256 + tid;
    int kc = idx / 2560, rem = idx % 2560;
    int n = rem >> 5, o = rem & 31;
    base[idx] = (_Float16)wm0[n * 4096 + kc * 32 + o];
  } else if (bid == 1280) {
    // K~ : L1-normalized gaussian rows, fp16 [4][64][64]
    int li = tid >> 6, i = tid & 63;
    float sg = (li == 0) ? s0[0] : (li == 1) ? s1[0] : (li == 2) ? s2[0] : s3[0];
    float denom = 2.0f * sg * sg;
    float sum = 0.0f;
    for (int j = 0; j < 64; ++j) {
      float d = (float)(i - j);
      sum += expf(-(d * d) / denom);
    }
    float inv = 1.0f / fmaxf(sum, 1e-12f);
    for (int j = 0; j < 64; ++j) {
      float d = (float)(i - j);
      base[KT_OFF + (li * 64 + i) * 64 + j] = (_Float16)(expf(-(d * d) / denom) * inv);
    }
  } else {
    // small layer weights, zero-padded to MFMA tiles (3840 halves total)
    for (int r = tid; r < 3840; r += 256) {
      float v;
      if (r < 1024)      { int o = r >> 6, c = r & 63;             v = (o < 8) ? w0[o * 64 + c] : 0.0f; }
      else if (r < 1280) { int q = r - 1024; int o = q >> 4, c = q & 15; v = (c < 8) ? w1[o * 8 + c] : 0.0f; }
      else if (r < 1792) { int q = r - 1280; int o = q >> 4, c = q & 15; v = w2[o * 16 + c]; }
      else               { int q = r - 1792; int o = q >> 5, c = q & 31; v = w3[o * 32 + c]; }
      base[W0P_OFF + r] = (_Float16)v;
    }
  }
}

__device__ __forceinline__ float leaky(float v) { return v > 0.0f ? v : 0.01f * v; }

// packed f32x4 -> f16x4 via v_cvt_pkrtz (2 instrs instead of 4 cvt + 2 pack)
__device__ __forceinline__ f16x4 pk4(float a, float b, float c, float d) {
  union { f16x4 v; hf2 p[2]; } u;
  u.p[0] = __builtin_amdgcn_cvt_pkrtz(a, b);
  u.p[1] = __builtin_amdgcn_cvt_pkrtz(c, d);
  return u.v;
}

// swizzled offset (halves) in an 8KB 64x64 fp16 buffer: 16B chunk j -> j ^ (row&7) ^ sx
__device__ __forceinline__ int swz(int sx, int row, int c) {
  return row * 64 + ((((c >> 3) ^ (row & 7) ^ sx) & 7) << 3) + (c & 7);
}

// sched fence: DS reads/writes may not cross (in-place transpose WAR hazard);
// VALU/SALU/MFMA/VMEM free to pipeline across stages (incl. weight prefetch).
#define DS_FENCE() __builtin_amdgcn_sched_barrier(0x7F)

__device__ __forceinline__ f16x8 ldf(const _Float16* p) { return *(const f16x8*)p; }
__device__ __forceinline__ f16x4 ldf4(const _Float16* p) { return *(const f16x4*)p; }

// stage A, K=32 chunks (b128 frags), PRELOADED weights, bias in C-operand.
template<int NT, int KC>
__device__ __forceinline__ void stage_a_pre(_Float16* P, int sx,
                                            const f16x8* wf, const float* bv,
                                            int lo, int hi) {
  DS_FENCE();        // prior stage's DS writes stay above
  f16x8 a[4][KC];
#pragma unroll
  for (int mt = 0; mt < 4; ++mt)
#pragma unroll
    for (int kc = 0; kc < KC; ++kc)
      a[mt][kc] = ldf(P + swz(sx, mt * 16 + lo, kc * 32 + hi * 8));
  DS_FENCE();        // all DS reads above; all DS writes below
#pragma unroll
  for (int mt = 0; mt < 4; ++mt)
#pragma unroll
    for (int nt = 0; nt < NT; ++nt) {
      f32x4 acc = {bv[nt], bv[nt], bv[nt], bv[nt]};
#pragma unroll
      for (int kc = 0; kc < KC; ++kc)
        acc = __builtin_amdgcn_mfma_f32_16x16x32_f16(a[mt][kc], wf[nt * KC + kc], acc, 0, 0, 0);
      *(f16x4*)(P + swz(sx, nt * 16 + lo, mt * 16 + hi * 4)) =
          pk4(acc[0], acc[1], acc[2], acc[3]);
    }
}

// stage A, K=16 (b64 frags, mfma_16x16x16f16) for C_in<=16 layers: reads only
// the 16 valid cols -> no stale-region reads, narrower LDS ops.
template<int NT>
__device__ __forceinline__ void stage_a16_pre(_Float16* P, int sx,
                                              const f16x4* wf, const float* bv,
                                              int lo, int hi) {
  DS_FENCE();
  f16x4 a[4];
#pragma unroll
  for (int mt = 0; mt < 4; ++mt)
    a[mt] = ldf4(P + swz(sx, mt * 16 + lo, hi * 4));
  DS_FENCE();
#pragma unroll
  for (int mt = 0; mt < 4; ++mt)
#pragma unroll
    for (int nt = 0; nt < NT; ++nt) {
      f32x4 acc = {bv[nt], bv[nt], bv[nt], bv[nt]};
      acc = __builtin_amdgcn_mfma_f32_16x16x16f16(a[mt], wf[nt], acc, 0, 0, 0);
      *(f16x4*)(P + swz(sx, nt * 16 + lo, mt * 16 + hi * 4)) =
          pk4(acc[0], acc[1], acc[2], acc[3]);
    }
}

// stage B with PRELOADED kb[8]: act_R[i][o] = leaky(K~ @ xpT^T)
template<int MT>
__device__ __forceinline__ void stage_b_pre(_Float16* P, int sx,
                                            const f16x8* kb, int lo, int hi) {
  DS_FENCE();
  f16x8 ax[MT][2];
#pragma unroll
  for (int ot = 0; ot < MT; ++ot)
#pragma unroll
    for (int kc = 0; kc < 2; ++kc)
      ax[ot][kc] = ldf(P + swz(sx, ot * 16 + lo, kc * 32 + hi * 8));
  DS_FENCE();
#pragma unroll
  for (int ot = 0; ot < MT; ++ot)
#pragma unroll
    for (int nt = 0; nt < 4; ++nt) {
      f32x4 acc = {0.0f, 0.0f, 0.0f, 0.0f};
#pragma unroll
      for (int kc = 0; kc < 2; ++kc)
        acc = __builtin_amdgcn_mfma_f32_16x16x32_f16(ax[ot][kc], kb[nt * 2 + kc], acc, 0, 0, 0);
      *(f16x4*)(P + swz(sx, nt * 16 + lo, ot * 16 + hi * 4)) =
          pk4(leaky(acc[0]), leaky(acc[1]), leaky(acc[2]), leaky(acc[3]));
    }
}

__global__ __launch_bounds__(512, 4)
void fused(const float* __restrict__ x,
           const float* __restrict__ bb0, const float* __restrict__ bb1,
           const float* __restrict__ bb2, const float* __restrict__ bb3,
           const _Float16* __restrict__ wsh,
           const float* __restrict__ bm0, const float* __restrict__ wm1,
           const float* __restrict__ bm1, float* __restrict__ out, int B) {
  __shared__ _Float16 lds[8][4096];   // 64KB: 8 samples x (64x64 fp16) -> 2 blocks/CU
  const int tid = threadIdx.x;
  const int wv = tid >> 6, lane = tid & 63;
  const int lo = lane & 15, hi = lane >> 4;
  const int smp0 = blockIdx.x * 8;
  int smp = smp0 + wv;  if (smp >= B) smp = B - 1;   // clamp; masked at final store
  _Float16* P = lds[wv];
  const int sx = wv;                  // swz masks &7 internally
  const _Float16* kt = wsh + KT_OFF;

  float bv0 = (lo < 8) ? bb0[lo] : 0.0f;
  float bv1 = bb1[lo];
  float bv2[2] = {bb2[lo], bb2[16 + lo]};
  float bv3[4] = {bb3[lo], bb3[16 + lo], bb3[32 + lo], bb3[48 + lo]};

  // ---- prefetch S0 (L0 weights) + S1 (kt0) fragments ----
  f16x8 wf0[2];
#pragma unroll
  for (int kc = 0; kc < 2; ++kc)
    wf0[kc] = ldf(wsh + W0P_OFF + lo * 64 + kc * 32 + hi * 8);
  f16x8 kbA[8];
#pragma unroll
  for (int nt = 0; nt < 4; ++nt)
#pragma unroll
    for (int kc = 0; kc < 2; ++kc)
      kbA[nt * 2 + kc] = ldf(kt + 0 * 4096 + (nt * 16 + lo) * 64 + kc * 32 + hi * 8);

  // ---- S0: layer-0 A direct from global fp32 x (no LDS staging) ----
  const float* xr = x + (size_t)smp * 4096;
  f16x8 a0[4][2];
#pragma unroll
  for (int mt = 0; mt < 4; ++mt)
#pragma unroll
    for (int kc = 0; kc < 2; ++kc) {
      const float4* p4 = (const float4*)(xr + (mt * 16 + lo) * 64 + kc * 32 + hi * 8);
      float4 v0 = p4[0], v1 = p4[1];
      union { f16x8 v; hf2 p[4]; } u;
      u.p[0] = __builtin_amdgcn_cvt_pkrtz(v0.x, v0.y);
      u.p[1] = __builtin_amdgcn_cvt_pkrtz(v0.z, v0.w);
      u.p[2] = __builtin_amdgcn_cvt_pkrtz(v1.x, v1.y);
      u.p[3] = __builtin_amdgcn_cvt_pkrtz(v1.z, v1.w);
      a0[mt][kc] = u.v;
    }
  DS_FENCE();          // S0 xpT writes are the first DS ops on this buffer
#pragma unroll
  for (int mt = 0; mt < 4; ++mt) {
    f32x4 acc = {bv0, bv0, bv0, bv0};
#pragma unroll
    for (int kc = 0; kc < 2; ++kc)
      acc = __builtin_amdgcn_mfma_f32_16x16x32_f16(a0[mt][kc], wf0[kc], acc, 0, 0, 0);
    *(f16x4*)(P + swz(sx, lo, mt * 16 + hi * 4)) =
        pk4(acc[0], acc[1], acc[2], acc[3]);       // nt = 0 only (8 feats)
  }

  // ---- pipelined chain: load stage i+1 frags, run stage i ----
  f16x4 wfA1[1];
  wfA1[0] = ldf4(wsh + W1P_OFF + lo * 16 + hi * 4);                    // S2 frags
  stage_b_pre<1>(P, sx, kbA, lo, hi);                                  // S1 (kt0)

  f16x8 kbB[8];
#pragma unroll
  for (int nt = 0; nt < 4; ++nt)
#pragma unroll
    for (int kc = 0; kc < 2; ++kc)
      kbB[nt * 2 + kc] = ldf(kt + 1 * 4096 + (nt * 16 + lo) * 64 + kc * 32 + hi * 8);
  stage_a16_pre<1>(P, sx, wfA1, &bv1, lo, hi);                         // S2 (w1)

  f16x4 wfA2[2];
#pragma unroll
  for (int nt = 0; nt < 2; ++nt)
    wfA2[nt] = ldf4(wsh + W2P_OFF + (nt * 16 + lo) * 16 + hi * 4);     // S4 frags
  stage_b_pre<1>(P, sx, kbB, lo, hi);                                  // S3 (kt1)

  f16x8 kbC[8];
#pragma unroll
  for (int nt = 0; nt < 4; ++nt)
#pragma unroll
    for (int kc = 0; kc < 2; ++kc)
      kbC[nt * 2 + kc] = ldf(kt + 2 * 4096 + (nt * 16 + lo) * 64 + kc * 32 + hi * 8);
  stage_a16_pre<2>(P, sx, wfA2, bv2, lo, hi);                          // S4 (w2)

  f16x8 wfA3[4];
#pragma unroll
  for (int nt = 0; nt < 4; ++nt)
    wfA3[nt] = ldf(wsh + W3P_OFF + (nt * 16 + lo) * 32 + hi * 8);      // S6 frags
  stage_b_pre<2>(P, sx, kbC, lo, hi);                                  // S5 (kt2)

  f16x8 kbD[8];
#pragma unroll
  for (int nt = 0; nt < 4; ++nt)
#pragma unroll
    for (int kc = 0; kc < 2; ++kc)
      kbD[nt * 2 + kc] = ldf(kt + 3 * 4096 + (nt * 16 + lo) * 64 + kc * 32 + hi * 8);
  stage_a_pre<4, 1>(P, sx, wfA3, bv3, lo, hi);                         // S6 (w3)

  stage_b_pre<4>(P, sx, kbD, lo, hi);                                  // S7 (kt3)

  __syncthreads();   // all 8 sample buffers complete before cross-wave dense reads

  // ---- phase D0: out80 = wm0 @ h.  A rows = 8 samples (of 16), 8-way K split ----
  f32x4 acc[5];
#pragma unroll
  for (int nt = 0; nt < 5; ++nt) { f32x4 z = {0.0f, 0.0f, 0.0f, 0.0f}; acc[nt] = z; }

  const _Float16* ap = &lds[lo & 7][0];
#pragma unroll 2
  for (int it = 0; it < 16; ++it) {
    int kc = wv * 16 + it;                 // 128 kc chunks of 32 halves
    int row = kc >> 1, cc = (kc & 1) * 32 + hi * 8;
    f16x8 a = *(const f16x8*)(ap + swz(lo & 7, row, cc));
    const _Float16* bp = wsh + (size_t)kc * 2560 + lo * 32 + hi * 8;
#pragma unroll
    for (int nt = 0; nt < 5; ++nt) {
      f16x8 b = *(const f16x8*)(bp + nt * 512);
      acc[nt] = __builtin_amdgcn_mfma_f32_16x16x32_f16(a, b, acc[nt], 0, 0, 0);
    }
  }
  __syncthreads();                         // all dense reads of lds done

  // partials into reused LDS: part[wv][m<8][80]  (8 waves x 640 floats = 20KB)
  float* scr = (float*)&lds[0][0];
  if (hi < 2) {
#pragma unroll
    for (int nt = 0; nt < 5; ++nt)
#pragma unroll
      for (int r = 0; r < 4; ++r)
        scr[wv * 640 + (hi * 4 + r) * 80 + nt * 16 + lo] = acc[nt][r];
  }
  __syncthreads();

  // reduce across 8 waves + bias + leaky -> h1[8][80]
  float* h1 = scr + 5120;
  for (int e = tid; e < 640; e += 512) {
    int m = e / 80, n = e - m * 80;
    float v = bm0[n];
#pragma unroll
    for (int w = 0; w < 8; ++w) v += scr[w * 640 + e];
    h1[e] = leaky(v);
  }
  __syncthreads();

  // ---- phase D1: out60 = wm1 @ h1 ----
  if (tid < 480) {
    int m = tid / 60, n = tid - m * 60;
    float v = bm1[n];
    const float4* hr = (const float4*)(h1 + m * 80);
    const float4* wr = (const float4*)(wm1 + n * 80);
#pragma unroll
    for (int k2 = 0; k2 < 20; ++k2) {
      float4 hv = hr[k2], wv4 = wr[k2];
      v += hv.x * wv4.x + hv.y * wv4.y + hv.z * wv4.z + hv.w * wv4.w;
    }
    int s = smp0 + m;
    if (s < B) out[(size_t)s * 60 + n] = leaky(v);
  }
}

extern "C" void kernel_launch(void* const* d_in, const int* in_sizes, int n_in,
                              void* d_out, int out_size, void* d_ws, size_t ws_size,
                              hipStream_t stream) {
  const float* x   = (const float*)d_in[0];
  const float* w0  = (const float*)d_in[1];
  const float* b0  = (const float*)d_in[2];
  const float* s0  = (const float*)d_in[3];
  const float* w1  = (const float*)d_in[4];
  const float* b1  = (const float*)d_in[5];
  const float* s1  = (const float*)d_in[6];
  const float* w2  = (const float*)d_in[7];
  const float* b2  = (const float*)d_in[8];
  const float* s2  = (const float*)d_in[9];
  const float* w3  = (const float*)d_in[10];
  const float* b3  = (const float*)d_in[11];
  const float* s3  = (const float*)d_in[12];
  const float* wm0 = (const float*)d_in[13];
  const float* bm0 = (const float*)d_in[14];
  const float* wm1 = (const float*)d_in[15];
  const float* bm1 = (const float*)d_in[16];
  float* out = (float*)d_out;
  _Float16* wsh = (_Float16*)d_ws;

  int B = in_sizes[0] / 4096;

  prep_all<<<1282, 256, 0, stream>>>(s0, s1, s2, s3, w0, w1, w2, w3, wm0, wsh);
  fused<<<(B + 7) / 8, 512, 0, stream>>>(x, b0, b1, b2, b3, wsh, bm0, wm1, bm1, out, B);
}